// Round 24
// baseline (98.907 us; speedup 1.0000x reference)
//
#include <hip/hip_runtime.h>
#include <hip/hip_bf16.h>

#define BB 64
#define TT 512
#define HH 768
#define LL 9
#define TS 516   // padded lgT row stride

#define LOG2E 1.44269504088896340736f
#define LN2   0.69314718055994530942f

#if __has_builtin(__builtin_amdgcn_logf)
#define LOG2F(x) __builtin_amdgcn_logf(x)
#else
#define LOG2F(x) __log2f(x)
#endif

// Broadcast lane I (0..15) of each 16-lane row to the whole row (row_newbcast).
template<int I>
__device__ __forceinline__ float dppb(float v) {
    return __uint_as_float((unsigned)__builtin_amdgcn_mov_dpp(
        (int)__float_as_uint(v), 0x150 + I, 0xF, 0xF, false));
}

// ---------------------------------------------------------------------------
// Kernel A: logits = relu(hidden @ W + b)   [32768 x 9]   (R22 version)
// ---------------------------------------------------------------------------
__global__ __launch_bounds__(256) void logits_kernel(
    const float* __restrict__ hidden,   // [32768][768]
    const float* __restrict__ W,        // [768][9]
    const float* __restrict__ bias,     // [9]
    float* __restrict__ logits,         // [32768][9]
    int* __restrict__ ctr)
{
    if (blockIdx.x == 0 && threadIdx.x == 0) atomicExch(ctr, 0);

    __shared__ __align__(16) float WT[LL][HH];
    __shared__ float bsh[LL];

    const int tid = threadIdx.x;
    for (int idx = tid; idx < HH * LL; idx += 256) {
        int k = idx / LL, l = idx % LL;
        WT[l][k] = W[idx];
    }
    if (tid < LL) bsh[tid] = bias[tid];
    __syncthreads();

    const int wave = tid >> 6;
    const int lane = tid & 63;
    const int grp  = lane >> 4;
    const int sl   = lane & 15;
    const long row = (long)blockIdx.x * 16 + wave * 4 + grp;
    const float* hrow = hidden + row * HH;

    float acc[LL];
#pragma unroll
    for (int l = 0; l < LL; ++l) acc[l] = 0.f;

#pragma unroll
    for (int it = 0; it < 12; ++it) {
        const int k = it * 64 + sl * 4;
        float4 h = *(const float4*)(hrow + k);
#pragma unroll
        for (int l = 0; l < LL; ++l) {
            float4 w4 = *(const float4*)(&WT[l][k]);
            acc[l] += h.x * w4.x + h.y * w4.y + h.z * w4.z + h.w * w4.w;
        }
    }

#pragma unroll
    for (int l = 0; l < LL; ++l) {
        float v = acc[l];
#pragma unroll
        for (int off = 8; off; off >>= 1) v += __shfl_xor(v, off, 64);
        acc[l] = v;
    }

    if (sl < LL) {
        float v = acc[0];
#pragma unroll
        for (int l = 1; l < LL; ++l) v = (sl == l) ? acc[l] : v;
        v += bsh[sl];
        v = v > 0.f ? v : 0.f;
        logits[row * LL + sl] = v;
    }
}

// ---------------------------------------------------------------------------
// Kernel B: per-batch CRF.  Block = 128 threads (2 waves).
//   wave 0: MERGED scan — row 0 hosts LSE chain, row 1 hosts Viterbi chain.
//           Independent chains interleave in one wave -> bubbles filled.
//   wave 1: waits, then bit-exact bp recovery + compose backtrace.
// ---------------------------------------------------------------------------
__global__ __launch_bounds__(128) void crf_kernel(
    const float* __restrict__ logits,   // [64][512][9]
    const float* __restrict__ trans,    // [9][9]
    const int*  __restrict__ tags,      // [64][512]
    const int*  __restrict__ lengths,   // [64]
    float* __restrict__ ll,             // [64]
    float* __restrict__ out_loss,       // [1]
    float* __restrict__ out_decode,     // [64][512] (floats)
    int* __restrict__ ctr)
{
    const int b    = blockIdx.x;
    const int tid  = threadIdx.x;
    const int wave = tid >> 6;
    const int lane = tid & 63;

    __shared__ __align__(16) float lgT[LL][TS];
    __shared__ __align__(16) int   tg[TT];
    __shared__ float trS[LL * LL];
    __shared__ __align__(16) float trST[LL][12];   // trST[j][i] = trans[i][j]
    __shared__ __align__(16) float alphaS[TT][12]; // viterbi alphas (cols 0-8)
    __shared__ float score_parts[4];
    __shared__ int   lt_sh;

    const int len = lengths[b];
    const float* lgg = logits + (size_t)b * TT * LL;
    for (int i = tid; i < (TT * LL) / 4; i += 128) {
        float4 v = ((const float4*)lgg)[i];
        int base = 4 * i;
        lgT[(base    ) % LL][(base    ) / LL] = v.x;
        lgT[(base + 1) % LL][(base + 1) / LL] = v.y;
        lgT[(base + 2) % LL][(base + 2) / LL] = v.z;
        lgT[(base + 3) % LL][(base + 3) / LL] = v.w;
    }
    {
        const int4* src = (const int4*)(tags + (size_t)b * TT);
        int4* dst = (int4*)tg;
        for (int i = tid; i < TT / 4; i += 128) dst[i] = src[i];
    }
    for (int idx = tid; idx < LL * LL; idx += 128) {
        trS[idx] = trans[idx];
        trST[idx % LL][idx / LL] = trans[idx];
    }
    __syncthreads();

    // ---- unary + binary gold scores (parallel over t, both waves) ----
    float u = 0.f, bs = 0.f;
    for (int t = tid; t < len; t += 128) u += lgT[tg[t]][t];
    for (int t = tid + 1; t < len; t += 128) bs += trS[tg[t - 1] * LL + tg[t]];
#pragma unroll
    for (int off = 32; off; off >>= 1) {
        u  += __shfl_xor(u, off, 64);
        bs += __shfl_xor(bs, off, 64);
    }
    if (lane == 0) { score_parts[wave * 2] = u; score_parts[wave * 2 + 1] = bs; }
    __syncthreads();

    if (wave == 0) {
        // ---------------- merged LSE + Viterbi scan ----------------
        const int sl = lane & 15;
        const int jj = (sl < LL) ? sl : (LL - 1);
        const int rowid = lane >> 4;
        const int acol = (rowid == 1) ? ((sl < LL) ? sl : 11) : 11;
        const float* rowj = &lgT[jj][0];

        float trc[LL];
#pragma unroll
        for (int i = 0; i < LL; ++i) trc[i] = trS[i * LL + jj];
        float E0 = exp2f(trc[0] * LOG2E), E1 = exp2f(trc[1] * LOG2E);
        float E2 = exp2f(trc[2] * LOG2E), E3 = exp2f(trc[3] * LOG2E);
        float E4 = exp2f(trc[4] * LOG2E), E5 = exp2f(trc[5] * LOG2E);
        float E6 = exp2f(trc[6] * LOG2E), E7 = exp2f(trc[7] * LOG2E);
        float E8 = exp2f(trc[8] * LOG2E);

        float Mlog = 0.f;
        float P0, P1, P2, P3, P4, P5, P6, P7, P8;
        float a0, a1, a2, a3, a4, a5, a6, a7, a8;
        {
            float lg0 = rowj[0];
            alphaS[0][acol] = lg0;
            float Pme = exp2f(lg0 * LOG2E);
            P0 = dppb<0>(Pme); P1 = dppb<1>(Pme); P2 = dppb<2>(Pme);
            P3 = dppb<3>(Pme); P4 = dppb<4>(Pme); P5 = dppb<5>(Pme);
            P6 = dppb<6>(Pme); P7 = dppb<7>(Pme); P8 = dppb<8>(Pme);
            a0 = dppb<0>(lg0); a1 = dppb<1>(lg0); a2 = dppb<2>(lg0);
            a3 = dppb<3>(lg0); a4 = dppb<4>(lg0); a5 = dppb<5>(lg0);
            a6 = dppb<6>(lg0); a7 = dppb<7>(lg0); a8 = dppb<8>(lg0);
        }

        // Merged step: LSE math == R20 LSTEPL; Viterbi math == R20 VSTEP3.
#define MSTEP(LGV, GV, TVAL)                                                 \
        { float p0 = P0 * E0, p1 = P1 * E1, p2 = P2 * E2;                    \
          float p3 = P3 * E3, p4 = P4 * E4, p5 = P5 * E5;                    \
          float p6 = P6 * E6, p7 = P7 * E7, p8 = P8 * E8;                    \
          float S = (((p0 + p1) + (p2 + p3)) + ((p4 + p5) + (p6 + p7)))      \
                    + p8;                                                    \
          float Pn = S * (GV);                                               \
          float s0 = a0 + trc[0], s1 = a1 + trc[1];                          \
          float s2 = a2 + trc[2], s3 = a3 + trc[3];                          \
          float s4 = a4 + trc[4], s5 = a5 + trc[5];                          \
          float s6 = a6 + trc[6], s7 = a7 + trc[7];                          \
          float s8 = a8 + trc[8];                                            \
          float m012 = fmaxf(fmaxf(s0, s1), s2);                             \
          float m345 = fmaxf(fmaxf(s3, s4), s5);                             \
          float m678 = fmaxf(fmaxf(s6, s7), s8);                             \
          float bv   = fmaxf(fmaxf(m012, m345), m678);                       \
          float ns = bv + (LGV);                                             \
          alphaS[TVAL][acol] = ns;                                           \
          P0 = dppb<0>(Pn); P1 = dppb<1>(Pn); P2 = dppb<2>(Pn);              \
          P3 = dppb<3>(Pn); P4 = dppb<4>(Pn); P5 = dppb<5>(Pn);              \
          P6 = dppb<6>(Pn); P7 = dppb<7>(Pn); P8 = dppb<8>(Pn);              \
          a0 = dppb<0>(ns); a1 = dppb<1>(ns); a2 = dppb<2>(ns);              \
          a3 = dppb<3>(ns); a4 = dppb<4>(ns); a5 = dppb<5>(ns);              \
          a6 = dppb<6>(ns); a7 = dppb<7>(ns); a8 = dppb<8>(ns); }

#define RENORM                                                               \
        { float mx = fmaxf(fmaxf(fmaxf(fmaxf(P0, P1), fmaxf(P2, P3)),       \
                                 fmaxf(fmaxf(P4, P5), fmaxf(P6, P7))), P8); \
          int ex = (int)((__float_as_uint(mx) >> 23) & 255u) - 127;         \
          float sc = __uint_as_float((unsigned)(127 - ex) << 23);           \
          P0 *= sc; P1 *= sc; P2 *= sc; P3 *= sc; P4 *= sc;                 \
          P5 *= sc; P6 *= sc; P7 *= sc; P8 *= sc;                           \
          Mlog += (float)ex; }

        int cb = 8;
        if (len >= 8) {
            float4 c0 = *(const float4*)(rowj);
            float4 c1 = *(const float4*)(rowj + 4);
            float g1 = exp2f(c0.y * LOG2E), g2 = exp2f(c0.z * LOG2E);
            float g3 = exp2f(c0.w * LOG2E), g4 = exp2f(c1.x * LOG2E);
            float g5 = exp2f(c1.y * LOG2E), g6 = exp2f(c1.z * LOG2E);
            float g7 = exp2f(c1.w * LOG2E);
            MSTEP(c0.y, g1, 1) MSTEP(c0.z, g2, 2) MSTEP(c0.w, g3, 3)
            MSTEP(c1.x, g4, 4) MSTEP(c1.y, g5, 5) MSTEP(c1.z, g6, 6)
            MSTEP(c1.w, g7, 7)

            float4 n0 = *(const float4*)(rowj + 8);
            float4 n1 = *(const float4*)(rowj + 12);
            for (; cb + 8 <= len; cb += 8) {
                float4 c0b = n0; float4 c1b = n1;
                if (cb + 8 < TT) {
                    n0 = *(const float4*)(rowj + cb + 8);
                    n1 = *(const float4*)(rowj + cb + 12);
                }
                float g0 = exp2f(c0b.x * LOG2E), g1b = exp2f(c0b.y * LOG2E);
                float g2b = exp2f(c0b.z * LOG2E), g3b = exp2f(c0b.w * LOG2E);
                float g4b = exp2f(c1b.x * LOG2E), g5b = exp2f(c1b.y * LOG2E);
                float g6b = exp2f(c1b.z * LOG2E), g7b = exp2f(c1b.w * LOG2E);
                RENORM
                MSTEP(c0b.x, g0, cb + 0)  MSTEP(c0b.y, g1b, cb + 1)
                MSTEP(c0b.z, g2b, cb + 2) MSTEP(c0b.w, g3b, cb + 3)
                MSTEP(c1b.x, g4b, cb + 4) MSTEP(c1b.y, g5b, cb + 5)
                MSTEP(c1b.z, g6b, cb + 6) MSTEP(c1b.w, g7b, cb + 7)
            }
        } else {
            cb = 1;
        }
        for (int t = cb; t < len; ++t) {
            float lgv = rowj[t];
            float g = exp2f(lgv * LOG2E);
            MSTEP(lgv, g, t)
        }

        // ---- LSE finish (row 0 lanes hold correct P) ----
        {
            float S = (((P0 + P1) + (P2 + P3)) + ((P4 + P5) + (P6 + P7)))
                      + P8;
            float log_norm = (Mlog + LOG2F(S)) * LN2;
            if (lane == 0) {
                float unary  = score_parts[0] + score_parts[2];
                float binary = score_parts[1] + score_parts[3];
                ll[b] = unary + binary - log_norm;
                __threadfence();
                int old = atomicAdd(ctr, 1);
                if (old == BB - 1) {
                    __threadfence();
                    float s = 0.f;
                    const volatile float* llv = (const volatile float*)ll;
                    for (int i = 0; i < BB; ++i) s += llv[i];
                    out_loss[0] = -s * (1.0f / 64.0f);
                }
            }
        }
        // ---- last_tag from row 1 (lane 16 holds correct a's) ----
        {
            float m012 = fmaxf(fmaxf(a0, a1), a2);
            float m345 = fmaxf(fmaxf(a3, a4), a5);
            float m678 = fmaxf(fmaxf(a6, a7), a8);
            float bv   = fmaxf(fmaxf(m012, m345), m678);
            int bi = 8;
            bi = (a7 == bv) ? 7 : bi;
            bi = (a6 == bv) ? 6 : bi;
            bi = (a5 == bv) ? 5 : bi;
            bi = (a4 == bv) ? 4 : bi;
            bi = (a3 == bv) ? 3 : bi;
            bi = (a2 == bv) ? 2 : bi;
            bi = (a1 == bv) ? 1 : bi;
            bi = (a0 == bv) ? 0 : bi;
            if (lane == 16) lt_sh = bi;
        }
    }
    __syncthreads();

    if (wave == 1) {
        // -------- parallel backpointer recovery (bit-exact re-adds) --------
        const int last_tag = lt_sh;
        const unsigned long long IDENT = 0x876543210ULL;
        unsigned long long f[8];
        const int t0 = lane * 8;
#pragma unroll
        for (int m2 = 0; m2 < 8; ++m2) {
            int t = t0 + m2;
            unsigned long long F = IDENT;
            if (t >= 1 && t < len) {
                float4 A0 = *(const float4*)&alphaS[t - 1][0];
                float4 A1 = *(const float4*)&alphaS[t - 1][4];
                float  A8 = alphaS[t - 1][8];
                F = 0ULL;
#pragma unroll
                for (int jj2 = 0; jj2 < LL; ++jj2) {
                    float4 T0 = *(const float4*)&trST[jj2][0];
                    float4 T1 = *(const float4*)&trST[jj2][4];
                    float  T8 = trST[jj2][8];
                    float s0 = A0.x + T0.x, s1 = A0.y + T0.y;
                    float s2 = A0.z + T0.z, s3 = A0.w + T0.w;
                    float s4 = A1.x + T1.x, s5 = A1.y + T1.y;
                    float s6 = A1.z + T1.z, s7 = A1.w + T1.w;
                    float s8 = A8 + T8;
                    float m012 = fmaxf(fmaxf(s0, s1), s2);
                    float m345 = fmaxf(fmaxf(s3, s4), s5);
                    float m678 = fmaxf(fmaxf(s6, s7), s8);
                    float bv   = fmaxf(fmaxf(m012, m345), m678);
                    int bi = 8;
                    bi = (s7 == bv) ? 7 : bi;
                    bi = (s6 == bv) ? 6 : bi;
                    bi = (s5 == bv) ? 5 : bi;
                    bi = (s4 == bv) ? 4 : bi;
                    bi = (s3 == bv) ? 3 : bi;
                    bi = (s2 == bv) ? 2 : bi;
                    bi = (s1 == bv) ? 1 : bi;
                    bi = (s0 == bv) ? 0 : bi;
                    F |= ((unsigned long long)bi) << (4 * jj2);
                }
            }
            f[m2] = F;
        }

        // ---------------- compose-based parallel backtrace ----------------
        unsigned long long h = f[7];
#pragma unroll
        for (int m2 = 6; m2 >= 0; --m2) {
            unsigned long long hn = 0ULL;
#pragma unroll
            for (int jj2 = 0; jj2 < LL; ++jj2) {
                int v = (int)((h >> (4 * jj2)) & 15ULL);
                int w = (int)((f[m2] >> (4 * v)) & 15ULL);
                hn |= ((unsigned long long)w) << (4 * jj2);
            }
            h = hn;
        }
        const unsigned hlo = (unsigned)h, hhi = (unsigned)(h >> 32);
        int tag = last_tag;
        int entry = last_tag;
        for (int l2 = 63; l2 >= 0; --l2) {
            unsigned glo = (unsigned)__builtin_amdgcn_readlane((int)hlo, l2);
            unsigned ghi = (unsigned)__builtin_amdgcn_readlane((int)hhi, l2);
            unsigned long long g = ((unsigned long long)ghi << 32) | glo;
            if (l2 == lane) entry = tag;
            tag = (int)((g >> (4 * tag)) & 15ULL);
        }
        float* dec = out_decode + (size_t)b * TT;
        int e = entry;
        {
            int t = t0 + 7;
            dec[t] = (t < len) ? (float)e : 0.f;
        }
#pragma unroll
        for (int m2 = 7; m2 >= 1; --m2) {
            e = (int)((f[m2] >> (4 * e)) & 15ULL);
            int t = t0 + m2 - 1;
            dec[t] = (t < len) ? (float)e : 0.f;
        }
    }
}

extern "C" void kernel_launch(void* const* d_in, const int* in_sizes, int n_in,
                              void* d_out, int out_size, void* d_ws, size_t ws_size,
                              hipStream_t stream)
{
    const float* hidden  = (const float*)d_in[0];
    const float* W       = (const float*)d_in[1];
    const float* bias    = (const float*)d_in[2];
    const float* trans   = (const float*)d_in[3];
    const int*   tags    = (const int*)d_in[4];
    const int*   lengths = (const int*)d_in[5];

    float* out = (float*)d_out;
    float* logits = (float*)d_ws;                       // 32768*9 floats
    float* ll     = logits + (size_t)BB * TT * LL;      // 64 floats
    int*   ctr    = (int*)(ll + 64);                    // loss counter

    logits_kernel<<<2048, 256, 0, stream>>>(hidden, W, bias, logits, ctr);
    crf_kernel<<<BB, 128, 0, stream>>>(logits, trans, tags, lengths, ll,
                                       out, out + 1, ctr);
}

// Round 25
// 67.106 us; speedup vs baseline: 1.4739x; 1.4739x over previous
//
#include <hip/hip_runtime.h>
#include <hip/hip_bf16.h>

#define BB 64
#define TT 512
#define HH 768
#define LL 9
#define TS 516   // padded lgT row stride

#define LOG2E 1.44269504088896340736f
#define LN2   0.69314718055994530942f

#if __has_builtin(__builtin_amdgcn_logf)
#define LOG2F(x) __builtin_amdgcn_logf(x)
#else
#define LOG2F(x) __log2f(x)
#endif

// Broadcast lane I (0..15) of each 16-lane row to the whole row (row_newbcast).
template<int I>
__device__ __forceinline__ float dppb(float v) {
    return __uint_as_float((unsigned)__builtin_amdgcn_mov_dpp(
        (int)__float_as_uint(v), 0x150 + I, 0xF, 0xF, false));
}

// Fused broadcast+add: s_i = (lane i of row)(NS) + T_i   (one DPP VOP2 each)
#define DPP9ADD(S0,S1,S2,S3,S4,S5,S6,S7,S8, NS, T0,T1,T2,T3,T4,T5,T6,T7,T8)  \
    asm("s_nop 1\n\t"                                                        \
        "v_add_f32_dpp %0, %9, %10 row_newbcast:0 row_mask:0xf bank_mask:0xf\n\t" \
        "v_add_f32_dpp %1, %9, %11 row_newbcast:1 row_mask:0xf bank_mask:0xf\n\t" \
        "v_add_f32_dpp %2, %9, %12 row_newbcast:2 row_mask:0xf bank_mask:0xf\n\t" \
        "v_add_f32_dpp %3, %9, %13 row_newbcast:3 row_mask:0xf bank_mask:0xf\n\t" \
        "v_add_f32_dpp %4, %9, %14 row_newbcast:4 row_mask:0xf bank_mask:0xf\n\t" \
        "v_add_f32_dpp %5, %9, %15 row_newbcast:5 row_mask:0xf bank_mask:0xf\n\t" \
        "v_add_f32_dpp %6, %9, %16 row_newbcast:6 row_mask:0xf bank_mask:0xf\n\t" \
        "v_add_f32_dpp %7, %9, %17 row_newbcast:7 row_mask:0xf bank_mask:0xf\n\t" \
        "v_add_f32_dpp %8, %9, %18 row_newbcast:8 row_mask:0xf bank_mask:0xf"     \
        : "=&v"(S0),"=&v"(S1),"=&v"(S2),"=&v"(S3),"=&v"(S4),                 \
          "=&v"(S5),"=&v"(S6),"=&v"(S7),"=&v"(S8)                            \
        : "v"(NS),"v"(T0),"v"(T1),"v"(T2),"v"(T3),"v"(T4),"v"(T5),           \
          "v"(T6),"v"(T7),"v"(T8))

// Fused broadcast+mul: p_i = (lane i of row)(PN) * E_i
#define DPP9MUL(S0,S1,S2,S3,S4,S5,S6,S7,S8, PN, T0,T1,T2,T3,T4,T5,T6,T7,T8)  \
    asm("s_nop 1\n\t"                                                        \
        "v_mul_f32_dpp %0, %9, %10 row_newbcast:0 row_mask:0xf bank_mask:0xf\n\t" \
        "v_mul_f32_dpp %1, %9, %11 row_newbcast:1 row_mask:0xf bank_mask:0xf\n\t" \
        "v_mul_f32_dpp %2, %9, %12 row_newbcast:2 row_mask:0xf bank_mask:0xf\n\t" \
        "v_mul_f32_dpp %3, %9, %13 row_newbcast:3 row_mask:0xf bank_mask:0xf\n\t" \
        "v_mul_f32_dpp %4, %9, %14 row_newbcast:4 row_mask:0xf bank_mask:0xf\n\t" \
        "v_mul_f32_dpp %5, %9, %15 row_newbcast:5 row_mask:0xf bank_mask:0xf\n\t" \
        "v_mul_f32_dpp %6, %9, %16 row_newbcast:6 row_mask:0xf bank_mask:0xf\n\t" \
        "v_mul_f32_dpp %7, %9, %17 row_newbcast:7 row_mask:0xf bank_mask:0xf\n\t" \
        "v_mul_f32_dpp %8, %9, %18 row_newbcast:8 row_mask:0xf bank_mask:0xf"     \
        : "=&v"(S0),"=&v"(S1),"=&v"(S2),"=&v"(S3),"=&v"(S4),                 \
          "=&v"(S5),"=&v"(S6),"=&v"(S7),"=&v"(S8)                            \
        : "v"(PN),"v"(T0),"v"(T1),"v"(T2),"v"(T3),"v"(T4),"v"(T5),           \
          "v"(T6),"v"(T7),"v"(T8))

// ---------------------------------------------------------------------------
// Kernel A: logits = relu(hidden @ W + b)   [32768 x 9]   (R22 version)
// ---------------------------------------------------------------------------
__global__ __launch_bounds__(256) void logits_kernel(
    const float* __restrict__ hidden,   // [32768][768]
    const float* __restrict__ W,        // [768][9]
    const float* __restrict__ bias,     // [9]
    float* __restrict__ logits,         // [32768][9]
    int* __restrict__ ctr)
{
    if (blockIdx.x == 0 && threadIdx.x == 0) atomicExch(ctr, 0);

    __shared__ __align__(16) float WT[LL][HH];
    __shared__ float bsh[LL];

    const int tid = threadIdx.x;
    for (int idx = tid; idx < HH * LL; idx += 256) {
        int k = idx / LL, l = idx % LL;
        WT[l][k] = W[idx];
    }
    if (tid < LL) bsh[tid] = bias[tid];
    __syncthreads();

    const int wave = tid >> 6;
    const int lane = tid & 63;
    const int grp  = lane >> 4;
    const int sl   = lane & 15;
    const long row = (long)blockIdx.x * 16 + wave * 4 + grp;
    const float* hrow = hidden + row * HH;

    float acc[LL];
#pragma unroll
    for (int l = 0; l < LL; ++l) acc[l] = 0.f;

#pragma unroll
    for (int it = 0; it < 12; ++it) {
        const int k = it * 64 + sl * 4;
        float4 h = *(const float4*)(hrow + k);
#pragma unroll
        for (int l = 0; l < LL; ++l) {
            float4 w4 = *(const float4*)(&WT[l][k]);
            acc[l] += h.x * w4.x + h.y * w4.y + h.z * w4.z + h.w * w4.w;
        }
    }

#pragma unroll
    for (int l = 0; l < LL; ++l) {
        float v = acc[l];
#pragma unroll
        for (int off = 8; off; off >>= 1) v += __shfl_xor(v, off, 64);
        acc[l] = v;
    }

    if (sl < LL) {
        float v = acc[0];
#pragma unroll
        for (int l = 1; l < LL; ++l) v = (sl == l) ? acc[l] : v;
        v += bsh[sl];
        v = v > 0.f ? v : 0.f;
        logits[row * LL + sl] = v;
    }
}

// ---------------------------------------------------------------------------
// Kernel B: per-batch CRF.  Block = 128 threads (2 waves).
//   wave 0: LSE scan (fused-DPP muls; single per-lane state Pn) + loss
//   wave 1: Viterbi value chain (fused-DPP adds) + bit-exact bp recovery
// ---------------------------------------------------------------------------
__global__ __launch_bounds__(128) void crf_kernel(
    const float* __restrict__ logits,   // [64][512][9]
    const float* __restrict__ trans,    // [9][9]
    const int*  __restrict__ tags,     // [64][512]
    const int*  __restrict__ lengths,   // [64]
    float* __restrict__ ll,             // [64]
    float* __restrict__ out_loss,       // [1]
    float* __restrict__ out_decode,     // [64][512] (floats)
    int* __restrict__ ctr)
{
    const int b    = blockIdx.x;
    const int tid  = threadIdx.x;
    const int wave = tid >> 6;
    const int lane = tid & 63;

    __shared__ __align__(16) float lgT[LL][TS];
    __shared__ __align__(16) int   tg[TT];
    __shared__ float trS[LL * LL];
    __shared__ __align__(16) float trST[LL][12];   // trST[j][i] = trans[i][j]
    __shared__ __align__(16) float alphaS[TT][12]; // viterbi alphas (cols 0-8)
    __shared__ float score_parts[4];

    const int len = lengths[b];
    const float* lgg = logits + (size_t)b * TT * LL;
    for (int i = tid; i < (TT * LL) / 4; i += 128) {
        float4 v = ((const float4*)lgg)[i];
        int base = 4 * i;
        lgT[(base    ) % LL][(base    ) / LL] = v.x;
        lgT[(base + 1) % LL][(base + 1) / LL] = v.y;
        lgT[(base + 2) % LL][(base + 2) / LL] = v.z;
        lgT[(base + 3) % LL][(base + 3) / LL] = v.w;
    }
    {
        const int4* src = (const int4*)(tags + (size_t)b * TT);
        int4* dst = (int4*)tg;
        for (int i = tid; i < TT / 4; i += 128) dst[i] = src[i];
    }
    for (int idx = tid; idx < LL * LL; idx += 128) {
        trS[idx] = trans[idx];
        trST[idx % LL][idx / LL] = trans[idx];
    }
    __syncthreads();

    // ---- unary + binary gold scores (parallel over t, both waves) ----
    float u = 0.f, bs = 0.f;
    for (int t = tid; t < len; t += 128) u += lgT[tg[t]][t];
    for (int t = tid + 1; t < len; t += 128) bs += trS[tg[t - 1] * LL + tg[t]];
#pragma unroll
    for (int off = 32; off; off >>= 1) {
        u  += __shfl_xor(u, off, 64);
        bs += __shfl_xor(bs, off, 64);
    }
    if (lane == 0) { score_parts[wave * 2] = u; score_parts[wave * 2 + 1] = bs; }
    __syncthreads();

    const int j = (lane < LL) ? lane : (LL - 1);
    float trc[LL];                 // transitions column j (natural units)
#pragma unroll
    for (int i = 0; i < LL; ++i) trc[i] = trS[i * LL + j];

    const float* rowj = &lgT[j][0];

    if (wave == 0) {
        // ------- linear-domain LSE scan, fused-DPP -------
        float E0 = exp2f(trc[0] * LOG2E), E1 = exp2f(trc[1] * LOG2E);
        float E2 = exp2f(trc[2] * LOG2E), E3 = exp2f(trc[3] * LOG2E);
        float E4 = exp2f(trc[4] * LOG2E), E5 = exp2f(trc[5] * LOG2E);
        float E6 = exp2f(trc[6] * LOG2E), E7 = exp2f(trc[7] * LOG2E);
        float E8 = exp2f(trc[8] * LOG2E);

        float Mlog = 0.f;
        float Pn = exp2f(rowj[0] * LOG2E);   // per-lane state: P_j

#define LSTEPF(GV)                                                           \
        { float p0,p1,p2,p3,p4,p5,p6,p7,p8;                                  \
          DPP9MUL(p0,p1,p2,p3,p4,p5,p6,p7,p8, Pn,                            \
                  E0,E1,E2,E3,E4,E5,E6,E7,E8);                               \
          float S = (((p0 + p1) + (p2 + p3)) + ((p4 + p5) + (p6 + p7)))      \
                    + p8;                                                    \
          Pn = S * (GV); }

        // exact pow2 renorm keyed on lane 0's exponent (uniform, exact)
#define RENORMF                                                              \
        { unsigned pb = (unsigned)__builtin_amdgcn_readfirstlane(            \
              (int)__float_as_uint(Pn));                                     \
          int ex = (int)((pb >> 23) & 255u) - 127;                           \
          float sc = __uint_as_float((unsigned)(127 - ex) << 23);            \
          Pn *= sc; Mlog += (float)ex; }

        int cb = 8;
        if (len >= 8) {
            float4 c0 = *(const float4*)(rowj);
            float4 c1 = *(const float4*)(rowj + 4);
            float g1 = exp2f(c0.y * LOG2E), g2 = exp2f(c0.z * LOG2E);
            float g3 = exp2f(c0.w * LOG2E), g4 = exp2f(c1.x * LOG2E);
            float g5 = exp2f(c1.y * LOG2E), g6 = exp2f(c1.z * LOG2E);
            float g7 = exp2f(c1.w * LOG2E);
            LSTEPF(g1) LSTEPF(g2) LSTEPF(g3)
            LSTEPF(g4) LSTEPF(g5) LSTEPF(g6) LSTEPF(g7)

            float4 n0 = *(const float4*)(rowj + 8);
            float4 n1 = *(const float4*)(rowj + 12);
            for (; cb + 8 <= len; cb += 8) {
                float4 c0b = n0; float4 c1b = n1;
                if (cb + 8 < TT) {
                    n0 = *(const float4*)(rowj + cb + 8);
                    n1 = *(const float4*)(rowj + cb + 12);
                }
                float g0 = exp2f(c0b.x * LOG2E), g1b = exp2f(c0b.y * LOG2E);
                float g2b = exp2f(c0b.z * LOG2E), g3b = exp2f(c0b.w * LOG2E);
                float g4b = exp2f(c1b.x * LOG2E), g5b = exp2f(c1b.y * LOG2E);
                float g6b = exp2f(c1b.z * LOG2E), g7b = exp2f(c1b.w * LOG2E);
                RENORMF
                LSTEPF(g0)  LSTEPF(g1b) LSTEPF(g2b) LSTEPF(g3b)
                LSTEPF(g4b) LSTEPF(g5b) LSTEPF(g6b) LSTEPF(g7b)
            }
        } else {
            cb = 1;
        }
        for (int t = cb; t < len; ++t) {
            float g = exp2f(rowj[t] * LOG2E);
            LSTEPF(g)
        }
        {
            // replicate final P vector (row-local) and finish
            float P0 = dppb<0>(Pn), P1 = dppb<1>(Pn), P2 = dppb<2>(Pn);
            float P3 = dppb<3>(Pn), P4 = dppb<4>(Pn), P5 = dppb<5>(Pn);
            float P6 = dppb<6>(Pn), P7 = dppb<7>(Pn), P8 = dppb<8>(Pn);
            float S = (((P0 + P1) + (P2 + P3)) + ((P4 + P5) + (P6 + P7)))
                      + P8;
            float log_norm = (Mlog + LOG2F(S)) * LN2;   // natural units
            if (lane == 0) {
                float unary  = score_parts[0] + score_parts[2];
                float binary = score_parts[1] + score_parts[3];
                ll[b] = unary + binary - log_norm;
                __threadfence();
                int old = atomicAdd(ctr, 1);
                if (old == BB - 1) {
                    __threadfence();
                    float s = 0.f;
                    const volatile float* llv = (const volatile float*)ll;
                    for (int i = 0; i < BB; ++i) s += llv[i];
                    out_loss[0] = -s * (1.0f / 64.0f);
                }
            }
        }
    } else {
        // -------- Viterbi value-only chain, fused-DPP (bit-exact) ----------
        const int acol = (lane < LL) ? lane : 11;   // lanes >=9 -> dummy col
        float ns = rowj[0];
        alphaS[0][acol] = ns;

#define VSTEPF(LGV, TVAL)                                                    \
        { float s0,s1,s2,s3,s4,s5,s6,s7,s8;                                  \
          DPP9ADD(s0,s1,s2,s3,s4,s5,s6,s7,s8, ns,                            \
                  trc[0],trc[1],trc[2],trc[3],trc[4],trc[5],trc[6],          \
                  trc[7],trc[8]);                                            \
          float m012 = fmaxf(fmaxf(s0, s1), s2);                             \
          float m345 = fmaxf(fmaxf(s3, s4), s5);                             \
          float m678 = fmaxf(fmaxf(s6, s7), s8);                             \
          float bv   = fmaxf(fmaxf(m012, m345), m678);                       \
          ns = bv + (LGV);                                                   \
          alphaS[TVAL][acol] = ns; }

        int cb = 8;
        if (len >= 8) {
            float4 c0 = *(const float4*)(rowj);
            float4 c1 = *(const float4*)(rowj + 4);
            VSTEPF(c0.y, 1) VSTEPF(c0.z, 2) VSTEPF(c0.w, 3)
            VSTEPF(c1.x, 4) VSTEPF(c1.y, 5) VSTEPF(c1.z, 6) VSTEPF(c1.w, 7)

            float4 n0 = *(const float4*)(rowj + 8);
            float4 n1 = *(const float4*)(rowj + 12);
            for (; cb + 8 <= len; cb += 8) {
                float4 c0b = n0; float4 c1b = n1;
                if (cb + 8 < TT) {
                    n0 = *(const float4*)(rowj + cb + 8);
                    n1 = *(const float4*)(rowj + cb + 12);
                }
                VSTEPF(c0b.x, cb + 0) VSTEPF(c0b.y, cb + 1)
                VSTEPF(c0b.z, cb + 2) VSTEPF(c0b.w, cb + 3)
                VSTEPF(c1b.x, cb + 4) VSTEPF(c1b.y, cb + 5)
                VSTEPF(c1b.z, cb + 6) VSTEPF(c1b.w, cb + 7)
            }
        } else {
            cb = 1;
        }
        for (int t = cb; t < len; ++t) {
            float lgv = rowj[t];
            VSTEPF(lgv, t)
        }

        // last_tag from replicated final alphas (row 0 correct); uniform.
        int last_tag;
        {
            float a0 = dppb<0>(ns), a1 = dppb<1>(ns), a2 = dppb<2>(ns);
            float a3 = dppb<3>(ns), a4 = dppb<4>(ns), a5 = dppb<5>(ns);
            float a6 = dppb<6>(ns), a7 = dppb<7>(ns), a8 = dppb<8>(ns);
            float m012 = fmaxf(fmaxf(a0, a1), a2);
            float m345 = fmaxf(fmaxf(a3, a4), a5);
            float m678 = fmaxf(fmaxf(a6, a7), a8);
            float bv   = fmaxf(fmaxf(m012, m345), m678);
            int bi = 8;
            bi = (a7 == bv) ? 7 : bi;
            bi = (a6 == bv) ? 6 : bi;
            bi = (a5 == bv) ? 5 : bi;
            bi = (a4 == bv) ? 4 : bi;
            bi = (a3 == bv) ? 3 : bi;
            bi = (a2 == bv) ? 2 : bi;
            bi = (a1 == bv) ? 1 : bi;
            bi = (a0 == bv) ? 0 : bi;
            last_tag = __builtin_amdgcn_readfirstlane(bi);
        }

        // -------- parallel backpointer recovery (bit-exact re-adds) --------
        const unsigned long long IDENT = 0x876543210ULL;
        unsigned long long f[8];
        const int t0 = lane * 8;
#pragma unroll
        for (int m2 = 0; m2 < 8; ++m2) {
            int t = t0 + m2;
            unsigned long long F = IDENT;
            if (t >= 1 && t < len) {
                float4 A0 = *(const float4*)&alphaS[t - 1][0];
                float4 A1 = *(const float4*)&alphaS[t - 1][4];
                float  A8 = alphaS[t - 1][8];
                F = 0ULL;
#pragma unroll
                for (int jj = 0; jj < LL; ++jj) {
                    float4 T0 = *(const float4*)&trST[jj][0];
                    float4 T1 = *(const float4*)&trST[jj][4];
                    float  T8 = trST[jj][8];
                    float s0 = A0.x + T0.x, s1 = A0.y + T0.y;
                    float s2 = A0.z + T0.z, s3 = A0.w + T0.w;
                    float s4 = A1.x + T1.x, s5 = A1.y + T1.y;
                    float s6 = A1.z + T1.z, s7 = A1.w + T1.w;
                    float s8 = A8 + T8;
                    float m012 = fmaxf(fmaxf(s0, s1), s2);
                    float m345 = fmaxf(fmaxf(s3, s4), s5);
                    float m678 = fmaxf(fmaxf(s6, s7), s8);
                    float bv   = fmaxf(fmaxf(m012, m345), m678);
                    int bi = 8;
                    bi = (s7 == bv) ? 7 : bi;
                    bi = (s6 == bv) ? 6 : bi;
                    bi = (s5 == bv) ? 5 : bi;
                    bi = (s4 == bv) ? 4 : bi;
                    bi = (s3 == bv) ? 3 : bi;
                    bi = (s2 == bv) ? 2 : bi;
                    bi = (s1 == bv) ? 1 : bi;
                    bi = (s0 == bv) ? 0 : bi;
                    F |= ((unsigned long long)bi) << (4 * jj);
                }
            }
            f[m2] = F;
        }

        // ---------------- compose-based parallel backtrace ----------------
        unsigned long long h = f[7];
#pragma unroll
        for (int m2 = 6; m2 >= 0; --m2) {
            unsigned long long hn = 0ULL;
#pragma unroll
            for (int jj = 0; jj < LL; ++jj) {
                int v = (int)((h >> (4 * jj)) & 15ULL);
                int w = (int)((f[m2] >> (4 * v)) & 15ULL);
                hn |= ((unsigned long long)w) << (4 * jj);
            }
            h = hn;
        }
        const unsigned hlo = (unsigned)h, hhi = (unsigned)(h >> 32);
        int tag = last_tag;
        int entry = last_tag;
        for (int l2 = 63; l2 >= 0; --l2) {
            unsigned glo = (unsigned)__builtin_amdgcn_readlane((int)hlo, l2);
            unsigned ghi = (unsigned)__builtin_amdgcn_readlane((int)hhi, l2);
            unsigned long long g = ((unsigned long long)ghi << 32) | glo;
            if (l2 == lane) entry = tag;
            tag = (int)((g >> (4 * tag)) & 15ULL);
        }
        float* dec = out_decode + (size_t)b * TT;
        int e = entry;
        {
            int t = t0 + 7;
            dec[t] = (t < len) ? (float)e : 0.f;
        }
#pragma unroll
        for (int m2 = 7; m2 >= 1; --m2) {
            e = (int)((f[m2] >> (4 * e)) & 15ULL);
            int t = t0 + m2 - 1;
            dec[t] = (t < len) ? (float)e : 0.f;
        }
    }
}

extern "C" void kernel_launch(void* const* d_in, const int* in_sizes, int n_in,
                              void* d_out, int out_size, void* d_ws, size_t ws_size,
                              hipStream_t stream)
{
    const float* hidden  = (const float*)d_in[0];
    const float* W       = (const float*)d_in[1];
    const float* bias    = (const float*)d_in[2];
    const float* trans   = (const float*)d_in[3];
    const int*   tags    = (const int*)d_in[4];
    const int*   lengths = (const int*)d_in[5];

    float* out = (float*)d_out;
    float* logits = (float*)d_ws;                       // 32768*9 floats
    float* ll     = logits + (size_t)BB * TT * LL;      // 64 floats
    int*   ctr    = (int*)(ll + 64);                    // loss counter

    logits_kernel<<<2048, 256, 0, stream>>>(hidden, W, bias, logits, ctr);
    crf_kernel<<<BB, 128, 0, stream>>>(logits, trans, tags, lengths, ll,
                                       out, out + 1, ctr);
}